// Round 1
// baseline (425.515 us; speedup 1.0000x reference)
//
#include <hip/hip_runtime.h>
#include <hip/hip_bf16.h>

// Problem: B=4096, T=200, D=64, H=32 attention pooling with score MLP.
// score(b,t) = W2 . sigmoid( qa[b] + k_t @ (W1b - W1c) )   (b2 dropped: softmax-invariant)
// where qa[b] = b1 + q_b @ (W1a + W1c).

#define B 4096
#define T 200
#define D 64
#define H 32
#define KP 68   // LDS pitch for key rows: 68 floats = 272 B, 16B-aligned, stride%32=4 -> 8-way max on b128

// ---------------- prep: WkT[j*64+i] = W1[(64+i)*32+j] - W1[(128+i)*32+j] ----------------
__global__ void prep_wk_kernel(const float* __restrict__ W1, float* __restrict__ wkT) {
    int n = blockIdx.x * 256 + threadIdx.x;       // 0..2047
    int j = n >> 6;
    int i = n & 63;
    wkT[n] = W1[(64 + i) * H + j] - W1[(128 + i) * H + j];
}

// ---------------- main: one block per batch row ----------------
__global__ __launch_bounds__(256) void attn_pool_kernel(
        const float* __restrict__ keys,   // [B,T,D]
        const int*   __restrict__ mask,   // [B,T] 0/1
        const float* __restrict__ query,  // [B,1,D]
        const float* __restrict__ W1,     // [192,32]
        const float* __restrict__ b1,     // [32]
        const float* __restrict__ W2,     // [32]
        const float* __restrict__ wkT,    // [32,64] precomputed (W1b - W1c)^T
        float*       __restrict__ out)    // [B,1,D]
{
    __shared__ float kt[T * KP];      // 54,400 B keys tile
    __shared__ float qa_lds[H];
    __shared__ float wts[T];
    __shared__ float redmax[4];
    __shared__ float redsum[4];
    __shared__ float part[256];

    const int tid = threadIdx.x;
    const int b   = blockIdx.x;

    // ---- stage keys[b] into LDS (coalesced float4 global reads) ----
    const float4* kp = reinterpret_cast<const float4*>(keys + (size_t)b * (T * D));
    for (int idx = tid; idx < (T * D) / 4; idx += 256) {
        float4 v = kp[idx];
        int flat = idx * 4;
        int t = flat >> 6;        // /D
        int i = flat & 63;        // %D
        *reinterpret_cast<float4*>(&kt[t * KP + i]) = v;
    }

    // ---- qa[j] = b1[j] + sum_i q[b][i] * (W1a[i][j] + W1c[i][j])  (32 threads) ----
    if (tid < H) {
        const int j = tid;
        float acc = b1[j];
        const float* qb = query + (size_t)b * D;   // q[b][i] uniform across block -> s_load
        #pragma unroll 8
        for (int i = 0; i < D; ++i) {
            float w = W1[i * H + j] + W1[(128 + i) * H + j];
            acc = fmaf(qb[i], w, acc);
        }
        qa_lds[j] = acc;
    }
    __syncthreads();

    // ---- per-t score: t = tid (t<200) ----
    const int t = tid;
    float s = -INFINITY;
    if (t < T) {
        // key row into registers
        float4 kreg[16];
        #pragma unroll
        for (int i4 = 0; i4 < 16; ++i4)
            kreg[i4] = *reinterpret_cast<const float4*>(&kt[t * KP + i4 * 4]);

        float sc = 0.0f;
        for (int j = 0; j < H; ++j) {
            const float* wrow = &wkT[j * D];   // uniform -> s_load_dwordx16
            float a0 = 0.f, a1 = 0.f, a2 = 0.f, a3 = 0.f;
            #pragma unroll
            for (int i4 = 0; i4 < 16; i4 += 4) {
                float4 k0 = kreg[i4 + 0];
                a0 = fmaf(k0.x, wrow[(i4+0)*4+0], a0);
                a0 = fmaf(k0.y, wrow[(i4+0)*4+1], a0);
                a0 = fmaf(k0.z, wrow[(i4+0)*4+2], a0);
                a0 = fmaf(k0.w, wrow[(i4+0)*4+3], a0);
                float4 k1 = kreg[i4 + 1];
                a1 = fmaf(k1.x, wrow[(i4+1)*4+0], a1);
                a1 = fmaf(k1.y, wrow[(i4+1)*4+1], a1);
                a1 = fmaf(k1.z, wrow[(i4+1)*4+2], a1);
                a1 = fmaf(k1.w, wrow[(i4+1)*4+3], a1);
                float4 k2 = kreg[i4 + 2];
                a2 = fmaf(k2.x, wrow[(i4+2)*4+0], a2);
                a2 = fmaf(k2.y, wrow[(i4+2)*4+1], a2);
                a2 = fmaf(k2.z, wrow[(i4+2)*4+2], a2);
                a2 = fmaf(k2.w, wrow[(i4+2)*4+3], a2);
                float4 k3 = kreg[i4 + 3];
                a3 = fmaf(k3.x, wrow[(i4+3)*4+0], a3);
                a3 = fmaf(k3.y, wrow[(i4+3)*4+1], a3);
                a3 = fmaf(k3.z, wrow[(i4+3)*4+2], a3);
                a3 = fmaf(k3.w, wrow[(i4+3)*4+3], a3);
            }
            float x = qa_lds[j] + ((a0 + a1) + (a2 + a3));
            // sigmoid(x) = 1 / (1 + 2^(-x*log2e))
            float e = exp2f(-x * 1.44269504088896340736f);
            float hval = __builtin_amdgcn_rcpf(1.0f + e);
            sc = fmaf(hval, W2[j], sc);
        }
        // mask (reference NEG_INF = -2^32+1)
        s = (mask[(size_t)b * T + t] != 0) ? sc : -4294967295.0f;
    }

    // ---- softmax over t (wave butterfly + LDS cross-wave) ----
    const int wv = tid >> 6;
    const int lane = tid & 63;

    float m = s;
    #pragma unroll
    for (int off = 32; off >= 1; off >>= 1)
        m = fmaxf(m, __shfl_xor(m, off, 64));
    if (lane == 0) redmax[wv] = m;
    __syncthreads();
    m = fmaxf(fmaxf(redmax[0], redmax[1]), fmaxf(redmax[2], redmax[3]));

    float e = (t < T) ? exp2f((s - m) * 1.44269504088896340736f) : 0.0f;
    float tot = e;
    #pragma unroll
    for (int off = 32; off >= 1; off >>= 1)
        tot += __shfl_xor(tot, off, 64);
    if (lane == 0) redsum[wv] = tot;
    __syncthreads();
    tot = (redsum[0] + redsum[1]) + (redsum[2] + redsum[3]);

    if (t < T) wts[t] = e / tot;
    __syncthreads();

    // ---- weighted key sum: wave w handles t in [50w, 50w+50), lane = d ----
    {
        float acc = 0.0f;
        const int t0 = wv * 50;
        #pragma unroll 5
        for (int tt = t0; tt < t0 + 50; ++tt)
            acc = fmaf(wts[tt], kt[tt * KP + lane], acc);   // wts broadcast, kt conflict-free
        part[wv * 64 + lane] = acc;
    }
    __syncthreads();
    if (tid < 64) {
        out[(size_t)b * D + tid] =
            ((part[tid] + part[64 + tid]) + (part[128 + tid] + part[192 + tid]));
    }
}

extern "C" void kernel_launch(void* const* d_in, const int* in_sizes, int n_in,
                              void* d_out, int out_size, void* d_ws, size_t ws_size,
                              hipStream_t stream) {
    const float* query = (const float*)d_in[0];
    const float* keys  = (const float*)d_in[1];
    const int*   mask  = (const int*)d_in[2];
    const float* W1    = (const float*)d_in[3];
    const float* b1    = (const float*)d_in[4];
    const float* W2    = (const float*)d_in[5];
    // d_in[6] = b2: softmax-invariant, unused.

    float* wkT = (float*)d_ws;   // 2048 floats = 8 KB

    prep_wk_kernel<<<8, 256, 0, stream>>>(W1, wkT);
    attn_pool_kernel<<<B, 256, 0, stream>>>(keys, mask, query, W1, b1, W2, wkT,
                                            (float*)d_out);
}

// Round 2
// 333.953 us; speedup vs baseline: 1.2742x; 1.2742x over previous
//
#include <hip/hip_runtime.h>
#include <hip/hip_bf16.h>

// B=4096, T=200, D=64, H=32 attention pooling with score MLP.
// score(b,t) = W2 . sigmoid( qa[b] + k_t @ (W1b - W1c) )    (b2 dropped: softmax-invariant)
// qa[b][j]  = b1[j] + q_b @ (W1a + W1c)[:,j]                (precomputed in prep kernel)

#define B 4096
#define T 200
#define D 64
#define H 32

// ws layout: [0, 2048)          wkT  = (W1b - W1c)^T   [32][64]
//            [2048, 2048+B*H)   qa   = b1 + q@(W1a+W1c) [B][32]
// total (2048 + 131072) * 4 = 532,480 bytes

// ---------------- prep: wkT and qa ----------------
__global__ __launch_bounds__(256) void prep_kernel(
        const float* __restrict__ W1,     // [192,32]
        const float* __restrict__ b1,     // [32]
        const float* __restrict__ query,  // [B,1,D]
        float*       __restrict__ ws)
{
    int n = blockIdx.x * 256 + threadIdx.x;
    if (blockIdx.x < 8) {
        // wkT[j*64+i] = W1[(64+i)*32+j] - W1[(128+i)*32+j]
        int j = n >> 6;
        int i = n & 63;
        ws[n] = W1[(64 + i) * H + j] - W1[(128 + i) * H + j];
    } else {
        int m = n - 2048;                 // 0 .. B*H-1
        int b = m >> 5;
        int j = m & 31;
        const float* qb = query + (size_t)b * D;
        float acc = b1[j];
        #pragma unroll 8
        for (int i = 0; i < D; ++i)
            acc = fmaf(qb[i], W1[i * H + j] + W1[(128 + i) * H + j], acc);
        ws[2048 + m] = acc;
    }
}

// ---------------- main: one block per batch row, barrier-free until softmax ----------------
__global__ __launch_bounds__(256, 5) void attn_pool_kernel(
        const float* __restrict__ keys,   // [B,T,D]
        const int*   __restrict__ mask,   // [B,T]
        const float* __restrict__ wkT,    // [32][64]
        const float* __restrict__ qa_all, // [B][32]
        const float* __restrict__ W2,     // [32]
        float*       __restrict__ out)    // [B,1,D]
{
    __shared__ float wts[T];
    __shared__ float redmax[4];
    __shared__ float redsum[4];
    __shared__ float part[256];

    const int tid  = threadIdx.x;
    const int b    = blockIdx.x;
    const int t    = tid;
    const int wv   = tid >> 6;
    const int lane = tid & 63;

    const float* qa = qa_all + (size_t)b * H;   // block-uniform -> s_load

    float s = -INFINITY;
    if (t < T) {
        // key row straight from global into registers (16 independent dwordx4)
        float4 kreg[16];
        const float4* kp = reinterpret_cast<const float4*>(keys + (size_t)b * (T * D) + t * D);
        #pragma unroll
        for (int i4 = 0; i4 < 16; ++i4)
            kreg[i4] = kp[i4];

        float sc = 0.0f;
        #pragma unroll 2
        for (int j = 0; j < H; ++j) {
            const float* wrow = &wkT[j * D];    // loop-uniform -> s_load_dwordx16
            float a0 = 0.f, a1 = 0.f, a2 = 0.f, a3 = 0.f;
            #pragma unroll
            for (int i4 = 0; i4 < 16; i4 += 4) {
                float4 k0 = kreg[i4 + 0];
                a0 = fmaf(k0.x, wrow[(i4+0)*4+0], a0);
                a0 = fmaf(k0.y, wrow[(i4+0)*4+1], a0);
                a0 = fmaf(k0.z, wrow[(i4+0)*4+2], a0);
                a0 = fmaf(k0.w, wrow[(i4+0)*4+3], a0);
                float4 k1 = kreg[i4 + 1];
                a1 = fmaf(k1.x, wrow[(i4+1)*4+0], a1);
                a1 = fmaf(k1.y, wrow[(i4+1)*4+1], a1);
                a1 = fmaf(k1.z, wrow[(i4+1)*4+2], a1);
                a1 = fmaf(k1.w, wrow[(i4+1)*4+3], a1);
                float4 k2 = kreg[i4 + 2];
                a2 = fmaf(k2.x, wrow[(i4+2)*4+0], a2);
                a2 = fmaf(k2.y, wrow[(i4+2)*4+1], a2);
                a2 = fmaf(k2.z, wrow[(i4+2)*4+2], a2);
                a2 = fmaf(k2.w, wrow[(i4+2)*4+3], a2);
                float4 k3 = kreg[i4 + 3];
                a3 = fmaf(k3.x, wrow[(i4+3)*4+0], a3);
                a3 = fmaf(k3.y, wrow[(i4+3)*4+1], a3);
                a3 = fmaf(k3.z, wrow[(i4+3)*4+2], a3);
                a3 = fmaf(k3.w, wrow[(i4+3)*4+3], a3);
            }
            float x = qa[j] + ((a0 + a1) + (a2 + a3));
            float e = exp2f(-x * 1.44269504088896340736f);        // sigmoid via exp2+rcp
            float hval = __builtin_amdgcn_rcpf(1.0f + e);
            sc = fmaf(hval, W2[j], sc);
        }
        s = (mask[(size_t)b * T + t] != 0) ? sc : -4294967295.0f; // reference NEG_INF
    }

    // ---- softmax over t (wave butterfly + LDS cross-wave) ----
    float m = s;
    #pragma unroll
    for (int off = 32; off >= 1; off >>= 1)
        m = fmaxf(m, __shfl_xor(m, off, 64));
    if (lane == 0) redmax[wv] = m;
    __syncthreads();
    m = fmaxf(fmaxf(redmax[0], redmax[1]), fmaxf(redmax[2], redmax[3]));

    float e = (t < T) ? exp2f((s - m) * 1.44269504088896340736f) : 0.0f;
    float tot = e;
    #pragma unroll
    for (int off = 32; off >= 1; off >>= 1)
        tot += __shfl_xor(tot, off, 64);
    if (lane == 0) redsum[wv] = tot;
    __syncthreads();
    tot = (redsum[0] + redsum[1]) + (redsum[2] + redsum[3]);

    if (t < T) wts[t] = e * __builtin_amdgcn_rcpf(tot);
    __syncthreads();

    // ---- weighted key sum: wave wv handles t in [50wv, 50wv+50), lane = d ----
    // coalesced global re-read (L1/L2-hot from phase 1), conflict-free
    {
        const float* krow = keys + (size_t)b * (T * D);
        float acc = 0.0f;
        const int t0 = wv * 50;
        #pragma unroll 5
        for (int tt = t0; tt < t0 + 50; ++tt)
            acc = fmaf(wts[tt], krow[tt * D + lane], acc);
        part[wv * 64 + lane] = acc;
    }
    __syncthreads();
    if (tid < 64) {
        out[(size_t)b * D + tid] =
            ((part[tid] + part[64 + tid]) + (part[128 + tid] + part[192 + tid]));
    }
}

extern "C" void kernel_launch(void* const* d_in, const int* in_sizes, int n_in,
                              void* d_out, int out_size, void* d_ws, size_t ws_size,
                              hipStream_t stream) {
    const float* query = (const float*)d_in[0];
    const float* keys  = (const float*)d_in[1];
    const int*   mask  = (const int*)d_in[2];
    const float* W1    = (const float*)d_in[3];
    const float* b1    = (const float*)d_in[4];
    const float* W2    = (const float*)d_in[5];
    // d_in[6] = b2: softmax-invariant, unused.

    float* ws  = (float*)d_ws;           // 2048 + B*H floats = 532,480 B
    float* wkT = ws;
    float* qa  = ws + 2048;

    // 8 blocks for wkT, 512 blocks for qa
    prep_kernel<<<8 + (B * H) / 256, 256, 0, stream>>>(W1, b1, query, ws);
    attn_pool_kernel<<<B, 256, 0, stream>>>(keys, mask, wkT, qa, W2, (float*)d_out);
}